// Round 15
// baseline (211.112 us; speedup 1.0000x reference)
//
#include <hip/hip_runtime.h>
#include <hip/hip_fp16.h>

#define FIN 64
#define HH 64
#define BLK 128
#define CIW 32       // ci values per bucket
#define CIWB 5       // log2(CIW): bin pack shift
#define T1 16384     // edges per hist/scatter block
#define RST 65       // rmxi row stride (65 breaks 4-group bank aliasing)
#define INVB 0xFFFFFFFFu

typedef _Float16 h2v __attribute__((ext_vector_type(2)));
typedef _Float16 f16x8 __attribute__((ext_vector_type(8)));
typedef float f32x4 __attribute__((ext_vector_type(4)));
union U4F { uint4 u; f16x8 h; };

__device__ __forceinline__ unsigned pack2(float x, float y) {
    __half2 h = __floats2half2_rn(x, y);     // .x -> low 16 bits
    union { __half2 h; unsigned u; } z; z.h = h;
    return z.u;
}
__device__ __forceinline__ float2 unpack2(unsigned u) {
    union { unsigned u; __half2 h; } z; z.u = u;
    return __half22float2(z.h);
}
__device__ __forceinline__ float fdot2f(unsigned a, unsigned b, float c) {
#if __has_builtin(__builtin_amdgcn_fdot2)
    union { unsigned u; h2v h; } za, zb; za.u = a; zb.u = b;
    return __builtin_amdgcn_fdot2(za.h, zb.h, c, false);
#else
    float2 fa = unpack2(a), fb = unpack2(b);
    return fmaf(fa.x, fb.x, fmaf(fa.y, fb.y, c));
#endif
}

// dot2 layer over own LDS row (32 u32 = 64 f16, XOR-swizzled 16B chunks)
__device__ __forceinline__ void dot2_layer(const unsigned* lds, int t,
        const unsigned* __restrict__ wp, const float* __restrict__ bias, float* h) {
    #pragma unroll
    for (int j = 0; j < 64; ++j) h[j] = bias[j];
    #pragma unroll 1
    for (int c = 0; c < 8; ++c) {
        uint4 hp = *reinterpret_cast<const uint4*>(&lds[(size_t)t * 32 + ((c ^ (t & 7)) << 2)]);
        const unsigned* w0 = wp + (4 * c + 0) * 64;
        const unsigned* w1 = wp + (4 * c + 1) * 64;
        const unsigned* w2 = wp + (4 * c + 2) * 64;
        const unsigned* w3 = wp + (4 * c + 3) * 64;
        #pragma unroll
        for (int j = 0; j < 64; ++j) {
            float a = fdot2f(hp.x, w0[j], h[j]);
            a = fdot2f(hp.y, w1[j], a);
            a = fdot2f(hp.z, w2[j], a);
            h[j] = fdot2f(hp.w, w3[j], a);
        }
    }
}

// ---------------- init helper (fallback path only) --------------------------
__global__ void zero_init(float* agg, int nagg, int* counts, int ncnt) {
    int i = blockIdx.x * blockDim.x + threadIdx.x;
    int stride = gridDim.x * blockDim.x;
    for (int k = i; k < nagg; k += stride) agg[k] = 0.f;
    for (int k = i; k < ncnt; k += stride) counts[k] = 0;
}

// ---- fused: blocks [0,NB1) histogram edge buckets -> lcnt row + bcnt;
// ---- blocks [NB1,NB1+32) pack weights. Independent halves.
__global__ __launch_bounds__(256) void histpack(
    const int* __restrict__ edge, int* bcnt, int* lcnt, int E, int NBUK, int NB1,
    const float* __restrict__ W1, const float* __restrict__ W2,
    const float* __restrict__ W3, const float* __restrict__ W4, unsigned* wp) {
    extern __shared__ int lh[];                  // NBUK ints (hist blocks only)
    int b = blockIdx.x, t = threadIdx.x;
    if (b < NB1) {
        for (int j = t; j < NBUK; j += 256) lh[j] = 0;
        __syncthreads();
        int lo = b * T1, hi = min(lo + T1, E);
        for (int e = lo + t; e < hi; e += 256) atomicAdd(&lh[edge[e] >> CIWB], 1);
        __syncthreads();
        int* lrow = lcnt + (size_t)b * NBUK;
        for (int j = t; j < NBUK; j += 256) {
            int c = lh[j];
            lrow[j] = c;                         // per-(block,bucket) count
            if (c) atomicAdd(&bcnt[j], c);
        }
    } else {
        int i = (b - NB1) * 256 + t;
        if (i >= 4 * 2048) return;
        int m = i >> 11, r = i & 2047;
        if (m == 1) {
            // B-frag for mfma_f32_16x16x32_f16: lane l, tile (ks,ni), pair p:
            // B[k0..k0+1][col], col = ni*16+(l&15), k0 = ks*32+(l>>4)*8+2p
            int tile = r >> 8;
            int l    = (r >> 2) & 63;
            int p    = r & 3;
            int ni = tile & 3, ks = tile >> 2;
            int col = ni * 16 + (l & 15);
            int k0  = ks * 32 + ((l >> 4) << 3) + 2 * p;
            wp[i] = pack2(W2[k0 * 64 + col], W2[(k0 + 1) * 64 + col]);
        } else {
            int kk = r >> 6, j = r & 63;
            const float* W = (m == 0) ? W1 : (m == 2) ? W3 : W4;
            wp[i] = pack2(W[(2 * kk) * 64 + j], W[(2 * kk + 1) * 64 + j]);
        }
    }
}

__global__ __launch_bounds__(1024) void scan_buckets(const int* __restrict__ bcnt,
                                                     int* bbase, int NBUK, int E) {
    const int T = 1024;
    int t = threadIdx.x;
    int C = (NBUK + T - 1) / T;
    int lo = t * C, hi = min(lo + C, NBUK);
    int s = 0;
    for (int i = lo; i < hi; ++i) s += bcnt[i];
    __shared__ int ss[T];
    ss[t] = s;
    __syncthreads();
    for (int off = 1; off < T; off <<= 1) {
        int v = (t >= off) ? ss[t - off] : 0;
        __syncthreads();
        ss[t] += v;
        __syncthreads();
    }
    int run = (t == 0) ? 0 : ss[t - 1];
    for (int i = lo; i < hi; ++i) {
        bbase[i] = run;
        run += bcnt[i];
    }
    if (t == 0) bbase[NBUK] = E;
}

// ---- 2D scan: lcnt[b][j] -> lofs[b][j] (in place): exclusive prefix over
// ---- blocks per bucket, based at bbase[j]. One thread per bucket.
__global__ __launch_bounds__(256) void scan2d(int* lcnt, const int* __restrict__ bbase,
                                              int NBUK, int NB1) {
    int j = blockIdx.x * 256 + threadIdx.x;
    if (j >= NBUK) return;
    int run = bbase[j];
    for (int b = 0; b < NB1; ++b) {
        int* p = lcnt + (size_t)b * NBUK + j;
        int c = *p;
        *p = run;
        run += c;
    }
}

// ---- fused: blocks [0,NB1) SINGLE-PASS scatter (cursors preloaded from
// ---- lofs); blocks [NB1,...) REGISTER-ONLY prepass.
__global__ __launch_bounds__(512) void scatter_prepass(
    const int* __restrict__ edge, const int* __restrict__ lofs, unsigned* bin,
    int E, int NBUK, int NB1,
    const float* __restrict__ last_features, const unsigned* __restrict__ w1p,
    const float* __restrict__ b1, uint4* pre1, int N) {
    extern __shared__ int cur[];                 // NBUK cursors
    int b = blockIdx.x, t = threadIdx.x;
    if (b < NB1) {
        const int* lrow = lofs + (size_t)b * NBUK;
        for (int j = t; j < NBUK; j += 512) cur[j] = lrow[j];
        __syncthreads();
        int lo = b * T1, hi = min(lo + T1, E);
        for (int e = lo + t; e < hi; e += 512) {
            int ci = edge[e];
            int bk = ci >> CIWB;
            int p = atomicAdd(&cur[bk], 1);
            bin[p] = (unsigned)(ci & (CIW - 1)) | ((unsigned)edge[E + e] << CIWB);
        }
    } else {
        int r = (b - NB1) * 512 + t;
        if (r >= N) return;

        const float4* xr = reinterpret_cast<const float4*>(last_features + (size_t)r * FIN);
        float h[64];
        #pragma unroll
        for (int j = 0; j < 64; ++j) h[j] = b1[j];

        // all f-indices compile-time per chunk -> pure register path, no LDS
        #pragma unroll 1
        for (int c = 0; c < 8; ++c) {
            float4 fa = xr[2 * c], fb = xr[2 * c + 1];
            unsigned hp0 = pack2(fa.x, fa.y);
            unsigned hp1 = pack2(fa.z, fa.w);
            unsigned hp2 = pack2(fb.x, fb.y);
            unsigned hp3 = pack2(fb.z, fb.w);
            const unsigned* w0 = w1p + (4 * c + 0) * 64;
            const unsigned* w1 = w1p + (4 * c + 1) * 64;
            const unsigned* w2 = w1p + (4 * c + 2) * 64;
            const unsigned* w3 = w1p + (4 * c + 3) * 64;
            #pragma unroll
            for (int j = 0; j < 64; ++j) {
                float a = fdot2f(hp0, w0[j], h[j]);
                a = fdot2f(hp1, w1[j], a);
                a = fdot2f(hp2, w2[j], a);
                h[j] = fdot2f(hp3, w3[j], a);
            }
        }

        uint4* out = pre1 + (size_t)r * 8;
        #pragma unroll
        for (int c = 0; c < 8; ++c) {
            uint4 o;
            o.x = pack2(h[8 * c + 0], h[8 * c + 1]);
            o.y = pack2(h[8 * c + 2], h[8 * c + 3]);
            o.z = pack2(h[8 * c + 4], h[8 * c + 5]);
            o.w = pack2(h[8 * c + 6], h[8 * c + 7]);
            out[c] = o;
        }
    }
}

// ------ fused edge kernel: 1 wave/block, depth-2 bin + depth-1 row ----------
// ------ software prefetch (256-VGPR budget), register-direct epilogue -------
__global__ __launch_bounds__(64, 2) void edge_mfma_fused(
    const float* __restrict__ last_coors,
    const float* __restrict__ current_coors,
    const unsigned* __restrict__ bin,      // packed: ci&(CIW-1) | li<<CIWB
    const uint4* __restrict__ pre1,
    const float* __restrict__ W1,          // rel rows at W1 + 64*64
    const float* __restrict__ b2,
    const unsigned* __restrict__ w2f,      // W2 in B-frag layout
    const int* __restrict__ bbase,
    float* agg, int M, int NBUK)
{
    __shared__ unsigned Ast[64 * 32];      // 8 KB A-stage (swizzled f16)
    __shared__ int rmxi[CIW * RST];        // ~8.3 KB running max (f32 bits, >=0)

    int bkt = blockIdx.x, t = threadIdx.x;
    int lo = bkt * CIW;
    int start = bbase[bkt], end = bbase[bkt + 1];

    for (int i = t; i < CIW * RST; i += 64) rmxi[i] = 0;

    // B fragments + bias (amortized over all tiles of this bucket)
    f16x8 bf[2][4];
    #pragma unroll
    for (int ks = 0; ks < 2; ++ks)
        #pragma unroll
        for (int ni = 0; ni < 4; ++ni) {
            U4F u;
            u.u = *reinterpret_cast<const uint4*>(w2f + (size_t)((ks * 4 + ni) * 64 + t) * 4);
            bf[ks][ni] = u.h;
        }
    float bb[4];
    #pragma unroll
    for (int ni = 0; ni < 4; ++ni) bb[ni] = b2[ni * 16 + (t & 15)];

    const float* rw = W1 + 64 * 64;

    // ---- prefetch pipeline: bvA = tile n, bvB = tile n+1; q/rr = tile n ----
    unsigned bvA = (start + t < end) ? bin[start + t] : INVB;
    unsigned bvB = (start + 64 + t < end) ? bin[start + 64 + t] : INVB;
    uint4 q[8] = {};
    float rr0 = 0.f, rr1 = 0.f, rr2 = 0.f;
    if (bvA != INVB) {
        int li = (int)(bvA >> CIWB);
        int ci0 = lo + (int)(bvA & (CIW - 1));
        const uint4* pr = pre1 + (size_t)li * 8;
        #pragma unroll
        for (int i = 0; i < 8; ++i) q[i] = pr[i];
        rr0 = last_coors[3 * li + 0] - current_coors[3 * ci0 + 0];
        rr1 = last_coors[3 * li + 1] - current_coors[3 * ci0 + 1];
        rr2 = last_coors[3 * li + 2] - current_coors[3 * ci0 + 2];
    }

    #pragma unroll 1
    for (int s = start; s < end; s += 64) {
        int nE = min(64, end - s);
        int ci = (bvA != INVB) ? (lo + (int)(bvA & (CIW - 1))) : lo;

        // issue bin two tiles ahead (coalesced, independent)
        unsigned bvC = (s + 128 + t < end) ? bin[s + 128 + t] : INVB;

        // h1 = relu(pre + rel @ W1b) -> A-stage, XOR-swizzled 16B chunks
        // (invalid lanes carry q=0, rr=0 -> zero rows)
        #pragma unroll
        for (int c = 0; c < 8; ++c) {
            unsigned qc[4] = {q[c].x, q[c].y, q[c].z, q[c].w};
            unsigned oc[4];
            #pragma unroll
            for (int p = 0; p < 4; ++p) {
                int j0 = 8 * c + 2 * p;
                float2 v = unpack2(qc[p]);
                v.x = fmaf(rr0, rw[j0],     fmaf(rr1, rw[64 + j0],     fmaf(rr2, rw[128 + j0],     v.x)));
                v.y = fmaf(rr0, rw[j0 + 1], fmaf(rr1, rw[64 + j0 + 1], fmaf(rr2, rw[128 + j0 + 1], v.y)));
                oc[p] = pack2(fmaxf(v.x, 0.f), fmaxf(v.y, 0.f));
            }
            uint4 o; o.x = oc[0]; o.y = oc[1]; o.z = oc[2]; o.w = oc[3];
            *reinterpret_cast<uint4*>(&Ast[(size_t)t * 32 + ((c ^ (t & 7)) << 2)]) = o;
        }

        // q/rr consumed -> prefetch NEXT tile's row + coors from bvB
        if (bvB != INVB) {
            int lin = (int)(bvB >> CIWB);
            int cin = lo + (int)(bvB & (CIW - 1));
            const uint4* prn = pre1 + (size_t)lin * 8;
            #pragma unroll
            for (int i = 0; i < 8; ++i) q[i] = prn[i];
            rr0 = last_coors[3 * lin + 0] - current_coors[3 * cin + 0];
            rr1 = last_coors[3 * lin + 1] - current_coors[3 * cin + 1];
            rr2 = last_coors[3 * lin + 2] - current_coors[3 * cin + 2];
        } else {
            #pragma unroll
            for (int i = 0; i < 8; ++i) q[i] = make_uint4(0, 0, 0, 0);
            rr0 = rr1 = rr2 = 0.f;
        }

        f32x4 acc[4][4];
        #pragma unroll
        for (int ni = 0; ni < 4; ++ni)
            #pragma unroll
            for (int mi = 0; mi < 4; ++mi)
                acc[mi][ni] = (f32x4){bb[ni], bb[ni], bb[ni], bb[ni]};

        // layer 2 GEMM: 64x64x64 = 2 K-steps x 4 M-tiles x 4 N-tiles MFMA
        #pragma unroll
        for (int ks = 0; ks < 2; ++ks) {
            #pragma unroll
            for (int mi = 0; mi < 4; ++mi) {
                int row = mi * 16 + (t & 15);
                int ch  = (ks * 4 + (t >> 4)) ^ (row & 7);   // undo A-stage swizzle
                U4F a;
                a.u = *reinterpret_cast<const uint4*>(&Ast[(size_t)row * 32 + (ch << 2)]);
                #pragma unroll
                for (int ni = 0; ni < 4; ++ni)
                    acc[mi][ni] = __builtin_amdgcn_mfma_f32_16x16x32_f16(
                        a.h, bf[ks][ni], acc[mi][ni], 0, 0, 0);
            }
        }

        // register-direct segmax: C layout row = mi*16+(t>>4)*4+r, col = ni*16+(t&15)
        #pragma unroll
        for (int mi = 0; mi < 4; ++mi) {
            #pragma unroll
            for (int r = 0; r < 4; ++r) {
                int row = mi * 16 + ((t >> 4) << 2) + r;
                int cir = __shfl(ci, row);
                if (row < nE) {
                    int* dst = &rmxi[(cir - lo) * RST + (t & 15)];
                    #pragma unroll
                    for (int ni = 0; ni < 4; ++ni)
                        atomicMax(&dst[ni * 16], __float_as_int(acc[mi][ni][r]));
                }
            }
        }

        bvA = bvB;
        bvB = bvC;
    }

    // block-exclusive contiguous writeout (covers empty buckets with 0;
    // rmxi bits are either 0 or a positive float -> reinterpret is exact)
    #pragma unroll
    for (int r = 0; r < CIW; ++r) {
        int gr = lo + r;
        if (gr < M) agg[(size_t)gr * 64 + t] = __int_as_float(rmxi[r * RST + t]);
    }
}

// ---------------- out MLP via dot2, in-place over d_out ---------------------
__global__ __launch_bounds__(64, 4) void out_mlp2(
    float* data,
    const unsigned* __restrict__ w3p, const float* __restrict__ b3,
    const unsigned* __restrict__ w4p, const float* __restrict__ b4, int M)
{
    __shared__ unsigned lds[64 * 32];
    int t = threadIdx.x;
    int r = blockIdx.x * 64 + t;
    if (r >= M) return;

    const float4* xr = reinterpret_cast<const float4*>(data + (size_t)r * HH);
    float4 f[16];
    #pragma unroll
    for (int i = 0; i < 16; ++i) f[i] = xr[i];

    #pragma unroll
    for (int c = 0; c < 8; ++c) {
        uint4 o;
        o.x = pack2(f[2 * c].x, f[2 * c].y);
        o.y = pack2(f[2 * c].z, f[2 * c].w);
        o.z = pack2(f[2 * c + 1].x, f[2 * c + 1].y);
        o.w = pack2(f[2 * c + 1].z, f[2 * c + 1].w);
        *reinterpret_cast<uint4*>(&lds[(size_t)t * 32 + ((c ^ (t & 7)) << 2)]) = o;
    }

    float h[64];
    dot2_layer(lds, t, w3p, b3, h);

    #pragma unroll
    for (int c = 0; c < 8; ++c) {
        uint4 o;
        o.x = pack2(fmaxf(h[8 * c + 0], 0.f), fmaxf(h[8 * c + 1], 0.f));
        o.y = pack2(fmaxf(h[8 * c + 2], 0.f), fmaxf(h[8 * c + 3], 0.f));
        o.z = pack2(fmaxf(h[8 * c + 4], 0.f), fmaxf(h[8 * c + 5], 0.f));
        o.w = pack2(fmaxf(h[8 * c + 6], 0.f), fmaxf(h[8 * c + 7], 0.f));
        *reinterpret_cast<uint4*>(&lds[(size_t)t * 32 + ((c ^ (t & 7)) << 2)]) = o;
    }

    float h2[64];
    dot2_layer(lds, t, w4p, b4, h2);

    float4* yr = reinterpret_cast<float4*>(data + (size_t)r * HH);
    #pragma unroll
    for (int c = 0; c < 16; ++c) {
        float4 o;
        o.x = fmaxf(h2[4 * c + 0], 0.f);
        o.y = fmaxf(h2[4 * c + 1], 0.f);
        o.z = fmaxf(h2[4 * c + 2], 0.f);
        o.w = fmaxf(h2[4 * c + 3], 0.f);
        yr[c] = o;
    }
}

// ================= last-resort fallback (round-2) path ======================
__global__ void hist_kernel(const int* __restrict__ edge, int* counts, int E) {
    int e = blockIdx.x * blockDim.x + threadIdx.x;
    if (e < E) atomicAdd(&counts[edge[e]], 1);
}

__global__ __launch_bounds__(1024) void scan_kernel(const int* __restrict__ counts,
                                                    int* cursor, int M) {
    const int T = 1024;
    int t = threadIdx.x;
    int C = (M + T - 1) / T;
    int lo = t * C, hi = min(lo + C, M);
    int s = 0;
    for (int i = lo; i < hi; ++i) s += counts[i];
    __shared__ int ss[T];
    ss[t] = s;
    __syncthreads();
    for (int off = 1; off < T; off <<= 1) {
        int v = (t >= off) ? ss[t - off] : 0;
        __syncthreads();
        ss[t] += v;
        __syncthreads();
    }
    int run = (t == 0) ? 0 : ss[t - 1];
    for (int i = lo; i < hi; ++i) {
        cursor[i] = run;
        run += counts[i];
    }
}

__global__ void scatter_kernel(const int* __restrict__ edge, int* cursor,
                               int* sorted, int E) {
    int e = blockIdx.x * blockDim.x + threadIdx.x;
    if (e < E) {
        int p = atomicAdd(&cursor[edge[e]], 1);
        sorted[p] = e;
    }
}

__global__ __launch_bounds__(BLK) void edge_mlp_sorted(
    const float* __restrict__ last_coors, const float* __restrict__ last_features,
    const float* __restrict__ current_coors, const int* __restrict__ edge,
    const int* __restrict__ sorted,
    const float* __restrict__ W1, const float* __restrict__ b1,
    const float* __restrict__ W2, const float* __restrict__ b2,
    float* agg, int E)
{
    __shared__ float hs[BLK][HH];
    __shared__ int cis[BLK];
    __shared__ int runStart[BLK + 1];
    __shared__ int wl[BLK / 64];
    int base = blockIdx.x * BLK, t = threadIdx.x;
    int nE = min(BLK, E - base);
    int ci = -1, li = 0;
    if (t < nE) { int es = sorted[base + t]; ci = edge[es]; li = edge[E + es]; }
    cis[t] = ci;
    if (t < nE) {
        float h1[HH];
        #pragma unroll
        for (int j = 0; j < HH; ++j) h1[j] = b1[j];
        const float4* xr = reinterpret_cast<const float4*>(last_features + (size_t)li * FIN);
        #pragma unroll 1
        for (int c = 0; c < FIN / 4; ++c) {
            float4 v = xr[c];
            const float* w = W1 + (size_t)(4 * c) * HH;
            #pragma unroll
            for (int j = 0; j < HH; ++j)
                h1[j] = fmaf(v.x, w[j], fmaf(v.y, w[HH + j],
                        fmaf(v.z, w[2 * HH + j], fmaf(v.w, w[3 * HH + j], h1[j]))));
        }
        {
            float r0 = last_coors[3 * li + 0] - current_coors[3 * ci + 0];
            float r1 = last_coors[3 * li + 1] - current_coors[3 * ci + 1];
            float r2 = last_coors[3 * li + 2] - current_coors[3 * ci + 2];
            const float* w = W1 + (size_t)64 * HH;
            #pragma unroll
            for (int j = 0; j < HH; ++j)
                h1[j] = fmaf(r0, w[j], fmaf(r1, w[HH + j], fmaf(r2, w[2 * HH + j], h1[j])));
        }
        #pragma unroll
        for (int c = 0; c < HH / 4; ++c) {
            float4 v;
            v.x = fmaxf(h1[4 * c + 0], 0.f); v.y = fmaxf(h1[4 * c + 1], 0.f);
            v.z = fmaxf(h1[4 * c + 2], 0.f); v.w = fmaxf(h1[4 * c + 3], 0.f);
            int cc = (c + t) & 15;
            *reinterpret_cast<float4*>(&hs[t][cc * 4]) = v;
        }
        float h2[HH];
        #pragma unroll
        for (int j = 0; j < HH; ++j) h2[j] = b2[j];
        #pragma unroll 1
        for (int c = 0; c < HH / 4; ++c) {
            int cc = (c + t) & 15;
            float4 v = *reinterpret_cast<const float4*>(&hs[t][cc * 4]);
            const float* w = W2 + (size_t)(4 * c) * HH;
            #pragma unroll
            for (int j = 0; j < HH; ++j)
                h2[j] = fmaf(v.x, w[j], fmaf(v.y, w[HH + j],
                        fmaf(v.z, w[2 * HH + j], fmaf(v.w, w[3 * HH + j], h2[j]))));
        }
        #pragma unroll
        for (int c = 0; c < HH / 4; ++c) {
            float4 v;
            v.x = fmaxf(h2[4 * c + 0], 0.f); v.y = fmaxf(h2[4 * c + 1], 0.f);
            v.z = fmaxf(h2[4 * c + 2], 0.f); v.w = fmaxf(h2[4 * c + 3], 0.f);
            int cc = (c + t) & 15;
            *reinterpret_cast<float4*>(&hs[t][cc * 4]) = v;
        }
    }
    __syncthreads();
    bool leader = (t < nE) && (t == 0 || cis[t] != cis[t - 1]);
    unsigned long long bal = __ballot(leader);
    int lane = t & 63, wid = t >> 6;
    if (lane == 63) wl[wid] = __popcll(bal);
    __syncthreads();
    int nruns = wl[0] + wl[1];
    if (leader) {
        int ord = __popcll(bal & ((1ull << lane) - 1)) + (wid ? wl[0] : 0);
        runStart[ord] = t;
    }
    if (t == 0) runStart[nruns] = nE;
    __syncthreads();
    int col = t & 63, half = t >> 6;
    int* aggi = reinterpret_cast<int*>(agg);
    for (int r = half; r < nruns; r += BLK / 64) {
        int s = runStart[r], e2 = runStart[r + 1];
        int c2 = cis[s];
        float m = 0.f;
        for (int k = s; k < e2; ++k) {
            int cc = ((col >> 2) + k) & 15;
            m = fmaxf(m, hs[k][cc * 4 + (col & 3)]);
        }
        int addr = c2 * HH + col;
        if (s == 0 || e2 == nE) {
            if (m > 0.f) atomicMax(&aggi[addr], __float_as_int(m));
        } else {
            agg[addr] = m;
        }
    }
}

__global__ __launch_bounds__(BLK) void out_mlp_f32(
    float* data, const float* __restrict__ W3, const float* __restrict__ b3,
    const float* __restrict__ W4, const float* __restrict__ b4, int M)
{
    __shared__ float hsm[BLK][HH];
    int r = blockIdx.x * BLK + threadIdx.x;
    if (r >= M) return;
    int t = threadIdx.x;
    const float4* xr = reinterpret_cast<const float4*>(data + (size_t)r * HH);
    float h[HH];
    #pragma unroll
    for (int j = 0; j < HH; ++j) h[j] = b3[j];
    #pragma unroll 1
    for (int c = 0; c < HH / 4; ++c) {
        float4 v = xr[c];
        const float* w = W3 + (size_t)(4 * c) * HH;
        #pragma unroll
        for (int j = 0; j < HH; ++j)
            h[j] = fmaf(v.x, w[j], fmaf(v.y, w[HH + j],
                   fmaf(v.z, w[2 * HH + j], fmaf(v.w, w[3 * HH + j], h[j]))));
    }
    #pragma unroll
    for (int c = 0; c < HH / 4; ++c) {
        float4 v;
        v.x = fmaxf(h[4 * c + 0], 0.f); v.y = fmaxf(h[4 * c + 1], 0.f);
        v.z = fmaxf(h[4 * c + 2], 0.f); v.w = fmaxf(h[4 * c + 3], 0.f);
        int cc = (c + t) & 15;
        *reinterpret_cast<float4*>(&hsm[t][cc * 4]) = v;
    }
    float h2[HH];
    #pragma unroll
    for (int j = 0; j < HH; ++j) h2[j] = b4[j];
    #pragma unroll 1
    for (int c = 0; c < HH / 4; ++c) {
        int cc = (c + t) & 15;
        float4 v = *reinterpret_cast<const float4*>(&hsm[t][cc * 4]);
        const float* w = W4 + (size_t)(4 * c) * HH;
        #pragma unroll
        for (int j = 0; j < HH; ++j)
            h2[j] = fmaf(v.x, w[j], fmaf(v.y, w[HH + j],
                    fmaf(v.z, w[2 * HH + j], fmaf(v.w, w[3 * HH + j], h2[j]))));
    }
    float* yr = data + (size_t)r * HH;
    #pragma unroll
    for (int c = 0; c < HH / 4; ++c) {
        float4 v;
        v.x = fmaxf(h2[4 * c + 0], 0.f); v.y = fmaxf(h2[4 * c + 1], 0.f);
        v.z = fmaxf(h2[4 * c + 2], 0.f); v.w = fmaxf(h2[4 * c + 3], 0.f);
        *reinterpret_cast<float4*>(&yr[4 * c]) = v;
    }
}

extern "C" void kernel_launch(void* const* d_in, const int* in_sizes, int n_in,
                              void* d_out, int out_size, void* d_ws, size_t ws_size,
                              hipStream_t stream) {
    const float* last_coors    = (const float*)d_in[0];
    const float* last_features = (const float*)d_in[1];
    const float* current_coors = (const float*)d_in[2];
    const int*   edge          = (const int*)d_in[3];
    const float* W1 = (const float*)d_in[4];  const float* b1 = (const float*)d_in[5];
    const float* W2 = (const float*)d_in[6];  const float* b2 = (const float*)d_in[7];
    const float* W3 = (const float*)d_in[8];  const float* b3 = (const float*)d_in[9];
    const float* W4 = (const float*)d_in[10]; const float* b4 = (const float*)d_in[11];

    int E = in_sizes[3] / 2;
    int M = in_sizes[2] / 3;
    int N = in_sizes[0] / 3;

    float* agg = (float*)d_out;
    int NBUK = (M + CIW - 1) / CIW;
    int NB1  = (E + T1 - 1) / T1;
    int PPB  = (N + 511) / 512;

    // ws layout (u32): bcnt[NBUK] | bbase[NBUK+1] | lcnt[NB1*NBUK] |
    //                  wp[8192] | bin[E] (packed u32) | pre1[32N]
    unsigned* ws = (unsigned*)d_ws;
    size_t offBbase = (size_t)NBUK;
    size_t offLcnt  = offBbase + NBUK + 1;
    size_t offWp    = (offLcnt + (size_t)NB1 * NBUK + 3) & ~(size_t)3;
    size_t offBin   = offWp + 4 * 2048;
    size_t offPre   = (offBin + (size_t)E + 3) & ~(size_t)3;
    size_t need     = (offPre + (size_t)N * 32) * 4;

    if (ws_size >= need && NBUK <= 4096) {
        int* bcnt     = (int*)ws;
        int* bbase    = (int*)(ws + offBbase);
        int* lcnt     = (int*)(ws + offLcnt);
        unsigned* wp  = ws + offWp;
        unsigned* bin = ws + offBin;
        uint4* pre1   = (uint4*)(ws + offPre);

        size_t smem1 = (size_t)NBUK * 4;

        hipMemsetAsync(bcnt, 0, (size_t)NBUK * 4, stream);
        histpack<<<NB1 + 32, 256, smem1, stream>>>(edge, bcnt, lcnt, E, NBUK, NB1,
                                                   W1, W2, W3, W4, wp);
        scan_buckets<<<1, 1024, 0, stream>>>(bcnt, bbase, NBUK, E);
        scan2d<<<(NBUK + 255) / 256, 256, 0, stream>>>(lcnt, bbase, NBUK, NB1);
        scatter_prepass<<<NB1 + PPB, 512, smem1, stream>>>(
            edge, lcnt, bin, E, NBUK, NB1, last_features, wp, b1, pre1, N);
        edge_mfma_fused<<<NBUK, 64, 0, stream>>>(
            last_coors, current_coors, bin, pre1,
            W1, b2, wp + 2048, bbase, agg, M, NBUK);
        out_mlp2<<<(M + 63) / 64, 64, 0, stream>>>(agg, wp + 4096, b3, wp + 6144, b4, M);
    } else {
        // fallback: round-2 path (counts | cursor | sorted[E])
        int* counts = (int*)ws;
        int* cursor = counts + (M + 1);
        int* sorted = cursor + (M + 1);
        zero_init<<<2048, 256, 0, stream>>>(agg, M * HH, counts, M + 1);
        hist_kernel<<<(E + 255) / 256, 256, 0, stream>>>(edge, counts, E);
        scan_kernel<<<1, 1024, 0, stream>>>(counts, cursor, M);
        scatter_kernel<<<(E + 255) / 256, 256, 0, stream>>>(edge, cursor, sorted, E);
        edge_mlp_sorted<<<(E + BLK - 1) / BLK, BLK, 0, stream>>>(
            last_coors, last_features, current_coors, edge, sorted,
            W1, b1, W2, b2, agg, E);
        out_mlp_f32<<<(M + BLK - 1) / BLK, BLK, 0, stream>>>(agg, W3, b3, W4, b4, M);
    }
}

// Round 16
// 188.188 us; speedup vs baseline: 1.1218x; 1.1218x over previous
//
#include <hip/hip_runtime.h>
#include <hip/hip_fp16.h>

#define FIN 64
#define HH 64
#define BLK 128
#define CIW 32       // ci values per bucket
#define CIWB 5       // log2(CIW): bin pack shift
#define T1 16384     // edges per hist/scatter block
#define RST 65       // rmxi row stride (65 breaks 4-group bank aliasing)
#define INVB 0xFFFFFFFFu

typedef _Float16 h2v __attribute__((ext_vector_type(2)));
typedef _Float16 f16x8 __attribute__((ext_vector_type(8)));
typedef float f32x4 __attribute__((ext_vector_type(4)));
union U4F { uint4 u; f16x8 h; };

__device__ __forceinline__ unsigned pack2(float x, float y) {
    __half2 h = __floats2half2_rn(x, y);     // .x -> low 16 bits
    union { __half2 h; unsigned u; } z; z.h = h;
    return z.u;
}
__device__ __forceinline__ float2 unpack2(unsigned u) {
    union { unsigned u; __half2 h; } z; z.u = u;
    return __half22float2(z.h);
}
__device__ __forceinline__ float fdot2f(unsigned a, unsigned b, float c) {
#if __has_builtin(__builtin_amdgcn_fdot2)
    union { unsigned u; h2v h; } za, zb; za.u = a; zb.u = b;
    return __builtin_amdgcn_fdot2(za.h, zb.h, c, false);
#else
    float2 fa = unpack2(a), fb = unpack2(b);
    return fmaf(fa.x, fb.x, fmaf(fa.y, fb.y, c));
#endif
}

// dot2 layer over own LDS row (32 u32 = 64 f16, XOR-swizzled 16B chunks)
__device__ __forceinline__ void dot2_layer(const unsigned* lds, int t,
        const unsigned* __restrict__ wp, const float* __restrict__ bias, float* h) {
    #pragma unroll
    for (int j = 0; j < 64; ++j) h[j] = bias[j];
    #pragma unroll 1
    for (int c = 0; c < 8; ++c) {
        uint4 hp = *reinterpret_cast<const uint4*>(&lds[(size_t)t * 32 + ((c ^ (t & 7)) << 2)]);
        const unsigned* w0 = wp + (4 * c + 0) * 64;
        const unsigned* w1 = wp + (4 * c + 1) * 64;
        const unsigned* w2 = wp + (4 * c + 2) * 64;
        const unsigned* w3 = wp + (4 * c + 3) * 64;
        #pragma unroll
        for (int j = 0; j < 64; ++j) {
            float a = fdot2f(hp.x, w0[j], h[j]);
            a = fdot2f(hp.y, w1[j], a);
            a = fdot2f(hp.z, w2[j], a);
            h[j] = fdot2f(hp.w, w3[j], a);
        }
    }
}

// ---------------- init helper (fallback path only) --------------------------
__global__ void zero_init(float* agg, int nagg, int* counts, int ncnt) {
    int i = blockIdx.x * blockDim.x + threadIdx.x;
    int stride = gridDim.x * blockDim.x;
    for (int k = i; k < nagg; k += stride) agg[k] = 0.f;
    for (int k = i; k < ncnt; k += stride) counts[k] = 0;
}

// ---- fused: blocks [0,NB1) histogram edge buckets; blocks [NB1,NB1+32) pack
// ---- weights (W1/W3/W4 dot2 layout; W2 MFMA B-frag layout). Independent.
__global__ __launch_bounds__(256) void histpack(
    const int* __restrict__ edge, int* bcnt, int E, int NBUK, int NB1,
    const float* __restrict__ W1, const float* __restrict__ W2,
    const float* __restrict__ W3, const float* __restrict__ W4, unsigned* wp) {
    extern __shared__ int lh[];                  // NBUK ints (hist blocks only)
    int b = blockIdx.x, t = threadIdx.x;
    if (b < NB1) {
        for (int j = t; j < NBUK; j += 256) lh[j] = 0;
        __syncthreads();
        int lo = b * T1, hi = min(lo + T1, E);
        for (int e = lo + t; e < hi; e += 256) atomicAdd(&lh[edge[e] >> CIWB], 1);
        __syncthreads();
        for (int j = t; j < NBUK; j += 256) {
            int c = lh[j];
            if (c) atomicAdd(&bcnt[j], c);
        }
    } else {
        int i = (b - NB1) * 256 + t;
        if (i >= 4 * 2048) return;
        int m = i >> 11, r = i & 2047;
        if (m == 1) {
            // B-frag for mfma_f32_16x16x32_f16: lane l, tile (ks,ni), pair p:
            // B[k0..k0+1][col], col = ni*16+(l&15), k0 = ks*32+(l>>4)*8+2p
            int tile = r >> 8;
            int l    = (r >> 2) & 63;
            int p    = r & 3;
            int ni = tile & 3, ks = tile >> 2;
            int col = ni * 16 + (l & 15);
            int k0  = ks * 32 + ((l >> 4) << 3) + 2 * p;
            wp[i] = pack2(W2[k0 * 64 + col], W2[(k0 + 1) * 64 + col]);
        } else {
            int kk = r >> 6, j = r & 63;
            const float* W = (m == 0) ? W1 : (m == 2) ? W3 : W4;
            wp[i] = pack2(W[(2 * kk) * 64 + j], W[(2 * kk + 1) * 64 + j]);
        }
    }
}

__global__ __launch_bounds__(1024) void scan_buckets(const int* __restrict__ bcnt,
                                                     int* bbase, int* bres,
                                                     int NBUK, int E) {
    const int T = 1024;
    int t = threadIdx.x;
    int C = (NBUK + T - 1) / T;
    int lo = t * C, hi = min(lo + C, NBUK);
    int s = 0;
    for (int i = lo; i < hi; ++i) s += bcnt[i];
    __shared__ int ss[T];
    ss[t] = s;
    __syncthreads();
    for (int off = 1; off < T; off <<= 1) {
        int v = (t >= off) ? ss[t - off] : 0;
        __syncthreads();
        ss[t] += v;
        __syncthreads();
    }
    int run = (t == 0) ? 0 : ss[t - 1];
    for (int i = lo; i < hi; ++i) {
        bbase[i] = run;
        bres[i] = run;
        run += bcnt[i];
    }
    if (t == 0) bbase[NBUK] = E;
}

// ---- fused: blocks [0,NB1) two-pass reserved scatter (512 thr); blocks
// ---- [NB1,...) REGISTER-ONLY prepass: pre1[n] = feat[n] @ W1a + b1 (f16).
__global__ __launch_bounds__(512) void scatter_prepass(
    const int* __restrict__ edge, int* bres, unsigned* bin, int E, int NBUK, int NB1,
    const float* __restrict__ last_features, const unsigned* __restrict__ w1p,
    const float* __restrict__ b1, uint4* pre1, int N) {
    extern __shared__ int sh[];                  // lh[NBUK] | lofs[NBUK]
    int b = blockIdx.x, t = threadIdx.x;
    if (b < NB1) {
        int* lh = sh;
        int* lofs = sh + NBUK;
        for (int j = t; j < NBUK; j += 512) lh[j] = 0;
        __syncthreads();
        int lo = b * T1, hi = min(lo + T1, E);
        for (int e = lo + t; e < hi; e += 512) atomicAdd(&lh[edge[e] >> CIWB], 1);
        __syncthreads();
        for (int j = t; j < NBUK; j += 512) {
            int c = lh[j];
            lofs[j] = c ? atomicAdd(&bres[j], c) : 0;
            lh[j] = 0;                           // reuse as running cursor
        }
        __syncthreads();
        for (int e = lo + t; e < hi; e += 512) {
            int ci = edge[e];
            int bk = ci >> CIWB;
            int p = lofs[bk] + atomicAdd(&lh[bk], 1);
            bin[p] = (unsigned)(ci & (CIW - 1)) | ((unsigned)edge[E + e] << CIWB);
        }
    } else {
        int r = (b - NB1) * 512 + t;
        if (r >= N) return;

        const float4* xr = reinterpret_cast<const float4*>(last_features + (size_t)r * FIN);
        float h[64];
        #pragma unroll
        for (int j = 0; j < 64; ++j) h[j] = b1[j];

        // all f-indices compile-time per chunk -> pure register path, no LDS
        #pragma unroll 1
        for (int c = 0; c < 8; ++c) {
            float4 fa = xr[2 * c], fb = xr[2 * c + 1];
            unsigned hp0 = pack2(fa.x, fa.y);
            unsigned hp1 = pack2(fa.z, fa.w);
            unsigned hp2 = pack2(fb.x, fb.y);
            unsigned hp3 = pack2(fb.z, fb.w);
            const unsigned* w0 = w1p + (4 * c + 0) * 64;
            const unsigned* w1 = w1p + (4 * c + 1) * 64;
            const unsigned* w2 = w1p + (4 * c + 2) * 64;
            const unsigned* w3 = w1p + (4 * c + 3) * 64;
            #pragma unroll
            for (int j = 0; j < 64; ++j) {
                float a = fdot2f(hp0, w0[j], h[j]);
                a = fdot2f(hp1, w1[j], a);
                a = fdot2f(hp2, w2[j], a);
                h[j] = fdot2f(hp3, w3[j], a);
            }
        }

        uint4* out = pre1 + (size_t)r * 8;
        #pragma unroll
        for (int c = 0; c < 8; ++c) {
            uint4 o;
            o.x = pack2(h[8 * c + 0], h[8 * c + 1]);
            o.y = pack2(h[8 * c + 2], h[8 * c + 3]);
            o.z = pack2(h[8 * c + 4], h[8 * c + 5]);
            o.w = pack2(h[8 * c + 6], h[8 * c + 7]);
            out[c] = o;
        }
    }
}

// ------ fused edge kernel: 1 wave/block, depth-2 bin + depth-1 row ----------
// ------ software prefetch (256-VGPR budget via launch_bounds(64,2); the -----
// ------ round-7 spill was under a 170-VGPR cap), register-direct epilogue ---
__global__ __launch_bounds__(64, 2) void edge_mfma_fused(
    const float* __restrict__ last_coors,
    const float* __restrict__ current_coors,
    const unsigned* __restrict__ bin,      // packed: ci&(CIW-1) | li<<CIWB
    const uint4* __restrict__ pre1,
    const float* __restrict__ W1,          // rel rows at W1 + 64*64
    const float* __restrict__ b2,
    const unsigned* __restrict__ w2f,      // W2 in B-frag layout
    const int* __restrict__ bbase,
    float* agg, int M, int NBUK)
{
    __shared__ unsigned Ast[64 * 32];      // 8 KB A-stage (swizzled f16)
    __shared__ int rmxi[CIW * RST];        // ~8.3 KB running max (f32 bits, >=0)

    int bkt = blockIdx.x, t = threadIdx.x;
    int lo = bkt * CIW;
    int start = bbase[bkt], end = bbase[bkt + 1];

    for (int i = t; i < CIW * RST; i += 64) rmxi[i] = 0;

    // B fragments + bias (amortized over all tiles of this bucket)
    f16x8 bf[2][4];
    #pragma unroll
    for (int ks = 0; ks < 2; ++ks)
        #pragma unroll
        for (int ni = 0; ni < 4; ++ni) {
            U4F u;
            u.u = *reinterpret_cast<const uint4*>(w2f + (size_t)((ks * 4 + ni) * 64 + t) * 4);
            bf[ks][ni] = u.h;
        }
    float bb[4];
    #pragma unroll
    for (int ni = 0; ni < 4; ++ni) bb[ni] = b2[ni * 16 + (t & 15)];

    const float* rw = W1 + 64 * 64;

    // ---- prefetch pipeline: bvA = tile n, bvB = tile n+1; q/rr = tile n ----
    unsigned bvA = (start + t < end) ? bin[start + t] : INVB;
    unsigned bvB = (start + 64 + t < end) ? bin[start + 64 + t] : INVB;
    uint4 q[8] = {};
    float rr0 = 0.f, rr1 = 0.f, rr2 = 0.f;
    if (bvA != INVB) {
        int li = (int)(bvA >> CIWB);
        int ci0 = lo + (int)(bvA & (CIW - 1));
        const uint4* pr = pre1 + (size_t)li * 8;
        #pragma unroll
        for (int i = 0; i < 8; ++i) q[i] = pr[i];
        rr0 = last_coors[3 * li + 0] - current_coors[3 * ci0 + 0];
        rr1 = last_coors[3 * li + 1] - current_coors[3 * ci0 + 1];
        rr2 = last_coors[3 * li + 2] - current_coors[3 * ci0 + 2];
    }

    #pragma unroll 1
    for (int s = start; s < end; s += 64) {
        int nE = min(64, end - s);
        int ci = (bvA != INVB) ? (lo + (int)(bvA & (CIW - 1))) : lo;

        // issue bin two tiles ahead (coalesced, independent)
        unsigned bvC = (s + 128 + t < end) ? bin[s + 128 + t] : INVB;

        // h1 = relu(pre + rel @ W1b) -> A-stage, XOR-swizzled 16B chunks
        // (invalid lanes carry q=0, rr=0 -> zero rows)
        #pragma unroll
        for (int c = 0; c < 8; ++c) {
            unsigned qc[4] = {q[c].x, q[c].y, q[c].z, q[c].w};
            unsigned oc[4];
            #pragma unroll
            for (int p = 0; p < 4; ++p) {
                int j0 = 8 * c + 2 * p;
                float2 v = unpack2(qc[p]);
                v.x = fmaf(rr0, rw[j0],     fmaf(rr1, rw[64 + j0],     fmaf(rr2, rw[128 + j0],     v.x)));
                v.y = fmaf(rr0, rw[j0 + 1], fmaf(rr1, rw[64 + j0 + 1], fmaf(rr2, rw[128 + j0 + 1], v.y)));
                oc[p] = pack2(fmaxf(v.x, 0.f), fmaxf(v.y, 0.f));
            }
            uint4 o; o.x = oc[0]; o.y = oc[1]; o.z = oc[2]; o.w = oc[3];
            *reinterpret_cast<uint4*>(&Ast[(size_t)t * 32 + ((c ^ (t & 7)) << 2)]) = o;
        }

        // q/rr consumed -> prefetch NEXT tile's row + coors from bvB
        // (latency hides under MFMA + epilogue below)
        if (bvB != INVB) {
            int lin = (int)(bvB >> CIWB);
            int cin = lo + (int)(bvB & (CIW - 1));
            const uint4* prn = pre1 + (size_t)lin * 8;
            #pragma unroll
            for (int i = 0; i < 8; ++i) q[i] = prn[i];
            rr0 = last_coors[3 * lin + 0] - current_coors[3 * cin + 0];
            rr1 = last_coors[3 * lin + 1] - current_coors[3 * cin + 1];
            rr2 = last_coors[3 * lin + 2] - current_coors[3 * cin + 2];
        } else {
            #pragma unroll
            for (int i = 0; i < 8; ++i) q[i] = make_uint4(0, 0, 0, 0);
            rr0 = rr1 = rr2 = 0.f;
        }

        f32x4 acc[4][4];
        #pragma unroll
        for (int ni = 0; ni < 4; ++ni)
            #pragma unroll
            for (int mi = 0; mi < 4; ++mi)
                acc[mi][ni] = (f32x4){bb[ni], bb[ni], bb[ni], bb[ni]};

        // layer 2 GEMM: 64x64x64 = 2 K-steps x 4 M-tiles x 4 N-tiles MFMA
        // (same-wave LDS ordering: compiler lgkmcnt waits, no barrier needed)
        #pragma unroll
        for (int ks = 0; ks < 2; ++ks) {
            #pragma unroll
            for (int mi = 0; mi < 4; ++mi) {
                int row = mi * 16 + (t & 15);
                int ch  = (ks * 4 + (t >> 4)) ^ (row & 7);   // undo A-stage swizzle
                U4F a;
                a.u = *reinterpret_cast<const uint4*>(&Ast[(size_t)row * 32 + (ch << 2)]);
                #pragma unroll
                for (int ni = 0; ni < 4; ++ni)
                    acc[mi][ni] = __builtin_amdgcn_mfma_f32_16x16x32_f16(
                        a.h, bf[ks][ni], acc[mi][ni], 0, 0, 0);
            }
        }

        // register-direct segmax: C layout row = mi*16+(t>>4)*4+r, col = ni*16+(t&15)
        // shfl pulls that row's ci; LDS int atomicMax on raw f32 bits (>=0 init)
        #pragma unroll
        for (int mi = 0; mi < 4; ++mi) {
            #pragma unroll
            for (int r = 0; r < 4; ++r) {
                int row = mi * 16 + ((t >> 4) << 2) + r;
                int cir = __shfl(ci, row);
                if (row < nE) {
                    int* dst = &rmxi[(cir - lo) * RST + (t & 15)];
                    #pragma unroll
                    for (int ni = 0; ni < 4; ++ni)
                        atomicMax(&dst[ni * 16], __float_as_int(acc[mi][ni][r]));
                }
            }
        }

        bvA = bvB;
        bvB = bvC;
    }

    // block-exclusive contiguous writeout (covers empty buckets with 0;
    // rmxi bits are either 0 or a positive float -> reinterpret is exact)
    #pragma unroll
    for (int r = 0; r < CIW; ++r) {
        int gr = lo + r;
        if (gr < M) agg[(size_t)gr * 64 + t] = __int_as_float(rmxi[r * RST + t]);
    }
}

// ---------------- out MLP via dot2, in-place over d_out ---------------------
__global__ __launch_bounds__(64, 4) void out_mlp2(
    float* data,
    const unsigned* __restrict__ w3p, const float* __restrict__ b3,
    const unsigned* __restrict__ w4p, const float* __restrict__ b4, int M)
{
    __shared__ unsigned lds[64 * 32];
    int t = threadIdx.x;
    int r = blockIdx.x * 64 + t;
    if (r >= M) return;

    const float4* xr = reinterpret_cast<const float4*>(data + (size_t)r * HH);
    float4 f[16];
    #pragma unroll
    for (int i = 0; i < 16; ++i) f[i] = xr[i];

    #pragma unroll
    for (int c = 0; c < 8; ++c) {
        uint4 o;
        o.x = pack2(f[2 * c].x, f[2 * c].y);
        o.y = pack2(f[2 * c].z, f[2 * c].w);
        o.z = pack2(f[2 * c + 1].x, f[2 * c + 1].y);
        o.w = pack2(f[2 * c + 1].z, f[2 * c + 1].w);
        *reinterpret_cast<uint4*>(&lds[(size_t)t * 32 + ((c ^ (t & 7)) << 2)]) = o;
    }

    float h[64];
    dot2_layer(lds, t, w3p, b3, h);

    #pragma unroll
    for (int c = 0; c < 8; ++c) {
        uint4 o;
        o.x = pack2(fmaxf(h[8 * c + 0], 0.f), fmaxf(h[8 * c + 1], 0.f));
        o.y = pack2(fmaxf(h[8 * c + 2], 0.f), fmaxf(h[8 * c + 3], 0.f));
        o.z = pack2(fmaxf(h[8 * c + 4], 0.f), fmaxf(h[8 * c + 5], 0.f));
        o.w = pack2(fmaxf(h[8 * c + 6], 0.f), fmaxf(h[8 * c + 7], 0.f));
        *reinterpret_cast<uint4*>(&lds[(size_t)t * 32 + ((c ^ (t & 7)) << 2)]) = o;
    }

    float h2[64];
    dot2_layer(lds, t, w4p, b4, h2);

    float4* yr = reinterpret_cast<float4*>(data + (size_t)r * HH);
    #pragma unroll
    for (int c = 0; c < 16; ++c) {
        float4 o;
        o.x = fmaxf(h2[4 * c + 0], 0.f);
        o.y = fmaxf(h2[4 * c + 1], 0.f);
        o.z = fmaxf(h2[4 * c + 2], 0.f);
        o.w = fmaxf(h2[4 * c + 3], 0.f);
        yr[c] = o;
    }
}

// ================= last-resort fallback (round-2) path ======================
__global__ void hist_kernel(const int* __restrict__ edge, int* counts, int E) {
    int e = blockIdx.x * blockDim.x + threadIdx.x;
    if (e < E) atomicAdd(&counts[edge[e]], 1);
}

__global__ __launch_bounds__(1024) void scan_kernel(const int* __restrict__ counts,
                                                    int* cursor, int M) {
    const int T = 1024;
    int t = threadIdx.x;
    int C = (M + T - 1) / T;
    int lo = t * C, hi = min(lo + C, M);
    int s = 0;
    for (int i = lo; i < hi; ++i) s += counts[i];
    __shared__ int ss[T];
    ss[t] = s;
    __syncthreads();
    for (int off = 1; off < T; off <<= 1) {
        int v = (t >= off) ? ss[t - off] : 0;
        __syncthreads();
        ss[t] += v;
        __syncthreads();
    }
    int run = (t == 0) ? 0 : ss[t - 1];
    for (int i = lo; i < hi; ++i) {
        cursor[i] = run;
        run += counts[i];
    }
}

__global__ void scatter_kernel(const int* __restrict__ edge, int* cursor,
                               int* sorted, int E) {
    int e = blockIdx.x * blockDim.x + threadIdx.x;
    if (e < E) {
        int p = atomicAdd(&cursor[edge[e]], 1);
        sorted[p] = e;
    }
}

__global__ __launch_bounds__(BLK) void edge_mlp_sorted(
    const float* __restrict__ last_coors, const float* __restrict__ last_features,
    const float* __restrict__ current_coors, const int* __restrict__ edge,
    const int* __restrict__ sorted,
    const float* __restrict__ W1, const float* __restrict__ b1,
    const float* __restrict__ W2, const float* __restrict__ b2,
    float* agg, int E)
{
    __shared__ float hs[BLK][HH];
    __shared__ int cis[BLK];
    __shared__ int runStart[BLK + 1];
    __shared__ int wl[BLK / 64];
    int base = blockIdx.x * BLK, t = threadIdx.x;
    int nE = min(BLK, E - base);
    int ci = -1, li = 0;
    if (t < nE) { int es = sorted[base + t]; ci = edge[es]; li = edge[E + es]; }
    cis[t] = ci;
    if (t < nE) {
        float h1[HH];
        #pragma unroll
        for (int j = 0; j < HH; ++j) h1[j] = b1[j];
        const float4* xr = reinterpret_cast<const float4*>(last_features + (size_t)li * FIN);
        #pragma unroll 1
        for (int c = 0; c < FIN / 4; ++c) {
            float4 v = xr[c];
            const float* w = W1 + (size_t)(4 * c) * HH;
            #pragma unroll
            for (int j = 0; j < HH; ++j)
                h1[j] = fmaf(v.x, w[j], fmaf(v.y, w[HH + j],
                        fmaf(v.z, w[2 * HH + j], fmaf(v.w, w[3 * HH + j], h1[j]))));
        }
        {
            float r0 = last_coors[3 * li + 0] - current_coors[3 * ci + 0];
            float r1 = last_coors[3 * li + 1] - current_coors[3 * ci + 1];
            float r2 = last_coors[3 * li + 2] - current_coors[3 * ci + 2];
            const float* w = W1 + (size_t)64 * HH;
            #pragma unroll
            for (int j = 0; j < HH; ++j)
                h1[j] = fmaf(r0, w[j], fmaf(r1, w[HH + j], fmaf(r2, w[2 * HH + j], h1[j])));
        }
        #pragma unroll
        for (int c = 0; c < HH / 4; ++c) {
            float4 v;
            v.x = fmaxf(h1[4 * c + 0], 0.f); v.y = fmaxf(h1[4 * c + 1], 0.f);
            v.z = fmaxf(h1[4 * c + 2], 0.f); v.w = fmaxf(h1[4 * c + 3], 0.f);
            int cc = (c + t) & 15;
            *reinterpret_cast<float4*>(&hs[t][cc * 4]) = v;
        }
        float h2[HH];
        #pragma unroll
        for (int j = 0; j < HH; ++j) h2[j] = b2[j];
        #pragma unroll 1
        for (int c = 0; c < HH / 4; ++c) {
            int cc = (c + t) & 15;
            float4 v = *reinterpret_cast<const float4*>(&hs[t][cc * 4]);
            const float* w = W2 + (size_t)(4 * c) * HH;
            #pragma unroll
            for (int j = 0; j < HH; ++j)
                h2[j] = fmaf(v.x, w[j], fmaf(v.y, w[HH + j],
                        fmaf(v.z, w[2 * HH + j], fmaf(v.w, w[3 * HH + j], h2[j]))));
        }
        #pragma unroll
        for (int c = 0; c < HH / 4; ++c) {
            float4 v;
            v.x = fmaxf(h2[4 * c + 0], 0.f); v.y = fmaxf(h2[4 * c + 1], 0.f);
            v.z = fmaxf(h2[4 * c + 2], 0.f); v.w = fmaxf(h2[4 * c + 3], 0.f);
            int cc = (c + t) & 15;
            *reinterpret_cast<float4*>(&hs[t][cc * 4]) = v;
        }
    }
    __syncthreads();
    bool leader = (t < nE) && (t == 0 || cis[t] != cis[t - 1]);
    unsigned long long bal = __ballot(leader);
    int lane = t & 63, wid = t >> 6;
    if (lane == 63) wl[wid] = __popcll(bal);
    __syncthreads();
    int nruns = wl[0] + wl[1];
    if (leader) {
        int ord = __popcll(bal & ((1ull << lane) - 1)) + (wid ? wl[0] : 0);
        runStart[ord] = t;
    }
    if (t == 0) runStart[nruns] = nE;
    __syncthreads();
    int col = t & 63, half = t >> 6;
    int* aggi = reinterpret_cast<int*>(agg);
    for (int r = half; r < nruns; r += BLK / 64) {
        int s = runStart[r], e2 = runStart[r + 1];
        int c2 = cis[s];
        float m = 0.f;
        for (int k = s; k < e2; ++k) {
            int cc = ((col >> 2) + k) & 15;
            m = fmaxf(m, hs[k][cc * 4 + (col & 3)]);
        }
        int addr = c2 * HH + col;
        if (s == 0 || e2 == nE) {
            if (m > 0.f) atomicMax(&aggi[addr], __float_as_int(m));
        } else {
            agg[addr] = m;
        }
    }
}

__global__ __launch_bounds__(BLK) void out_mlp_f32(
    float* data, const float* __restrict__ W3, const float* __restrict__ b3,
    const float* __restrict__ W4, const float* __restrict__ b4, int M)
{
    __shared__ float hsm[BLK][HH];
    int r = blockIdx.x * BLK + threadIdx.x;
    if (r >= M) return;
    int t = threadIdx.x;
    const float4* xr = reinterpret_cast<const float4*>(data + (size_t)r * HH);
    float h[HH];
    #pragma unroll
    for (int j = 0; j < HH; ++j) h[j] = b3[j];
    #pragma unroll 1
    for (int c = 0; c < HH / 4; ++c) {
        float4 v = xr[c];
        const float* w = W3 + (size_t)(4 * c) * HH;
        #pragma unroll
        for (int j = 0; j < HH; ++j)
            h[j] = fmaf(v.x, w[j], fmaf(v.y, w[HH + j],
                   fmaf(v.z, w[2 * HH + j], fmaf(v.w, w[3 * HH + j], h[j]))));
    }
    #pragma unroll
    for (int c = 0; c < HH / 4; ++c) {
        float4 v;
        v.x = fmaxf(h[4 * c + 0], 0.f); v.y = fmaxf(h[4 * c + 1], 0.f);
        v.z = fmaxf(h[4 * c + 2], 0.f); v.w = fmaxf(h[4 * c + 3], 0.f);
        int cc = (c + t) & 15;
        *reinterpret_cast<float4*>(&hsm[t][cc * 4]) = v;
    }
    float h2[HH];
    #pragma unroll
    for (int j = 0; j < HH; ++j) h2[j] = b4[j];
    #pragma unroll 1
    for (int c = 0; c < HH / 4; ++c) {
        int cc = (c + t) & 15;
        float4 v = *reinterpret_cast<const float4*>(&hsm[t][cc * 4]);
        const float* w = W4 + (size_t)(4 * c) * HH;
        #pragma unroll
        for (int j = 0; j < HH; ++j)
            h2[j] = fmaf(v.x, w[j], fmaf(v.y, w[HH + j],
                    fmaf(v.z, w[2 * HH + j], fmaf(v.w, w[3 * HH + j], h2[j]))));
    }
    float* yr = data + (size_t)r * HH;
    #pragma unroll
    for (int c = 0; c < HH / 4; ++c) {
        float4 v;
        v.x = fmaxf(h2[4 * c + 0], 0.f); v.y = fmaxf(h2[4 * c + 1], 0.f);
        v.z = fmaxf(h2[4 * c + 2], 0.f); v.w = fmaxf(h2[4 * c + 3], 0.f);
        *reinterpret_cast<float4*>(&yr[4 * c]) = v;
    }
}

extern "C" void kernel_launch(void* const* d_in, const int* in_sizes, int n_in,
                              void* d_out, int out_size, void* d_ws, size_t ws_size,
                              hipStream_t stream) {
    const float* last_coors    = (const float*)d_in[0];
    const float* last_features = (const float*)d_in[1];
    const float* current_coors = (const float*)d_in[2];
    const int*   edge          = (const int*)d_in[3];
    const float* W1 = (const float*)d_in[4];  const float* b1 = (const float*)d_in[5];
    const float* W2 = (const float*)d_in[6];  const float* b2 = (const float*)d_in[7];
    const float* W3 = (const float*)d_in[8];  const float* b3 = (const float*)d_in[9];
    const float* W4 = (const float*)d_in[10]; const float* b4 = (const float*)d_in[11];

    int E = in_sizes[3] / 2;
    int M = in_sizes[2] / 3;
    int N = in_sizes[0] / 3;

    float* agg = (float*)d_out;
    int NBUK = (M + CIW - 1) / CIW;
    int NB1  = (E + T1 - 1) / T1;
    int PPB  = (N + 511) / 512;

    // ws layout (u32): bcnt[NBUK] | bbase[NBUK+1] | bres[NBUK] |
    //                  wp[8192] | bin[E] (packed u32) | pre1[32N]
    unsigned* ws = (unsigned*)d_ws;
    size_t offBbase = (size_t)NBUK;
    size_t offBres  = offBbase + NBUK + 1;
    size_t offWp    = (offBres + NBUK + 3) & ~(size_t)3;
    size_t offBin   = offWp + 4 * 2048;
    size_t offPre   = (offBin + (size_t)E + 3) & ~(size_t)3;
    size_t need     = (offPre + (size_t)N * 32) * 4;

    if (ws_size >= need && NBUK <= 4096) {
        int* bcnt     = (int*)ws;
        int* bbase    = (int*)(ws + offBbase);
        int* bres     = (int*)(ws + offBres);
        unsigned* wp  = ws + offWp;
        unsigned* bin = ws + offBin;
        uint4* pre1   = (uint4*)(ws + offPre);

        size_t smem2 = 2 * (size_t)NBUK * 4;

        hipMemsetAsync(bcnt, 0, (size_t)NBUK * 4, stream);
        histpack<<<NB1 + 32, 256, NBUK * 4, stream>>>(edge, bcnt, E, NBUK, NB1,
                                                      W1, W2, W3, W4, wp);
        scan_buckets<<<1, 1024, 0, stream>>>(bcnt, bbase, bres, NBUK, E);
        scatter_prepass<<<NB1 + PPB, 512, smem2, stream>>>(
            edge, bres, bin, E, NBUK, NB1, last_features, wp, b1, pre1, N);
        edge_mfma_fused<<<NBUK, 64, 0, stream>>>(
            last_coors, current_coors, bin, pre1,
            W1, b2, wp + 2048, bbase, agg, M, NBUK);
        out_mlp2<<<(M + 63) / 64, 64, 0, stream>>>(agg, wp + 4096, b3, wp + 6144, b4, M);
    } else {
        // fallback: round-2 path (counts | cursor | sorted[E])
        int* counts = (int*)ws;
        int* cursor = counts + (M + 1);
        int* sorted = cursor + (M + 1);
        zero_init<<<2048, 256, 0, stream>>>(agg, M * HH, counts, M + 1);
        hist_kernel<<<(E + 255) / 256, 256, 0, stream>>>(edge, counts, E);
        scan_kernel<<<1, 1024, 0, stream>>>(counts, cursor, M);
        scatter_kernel<<<(E + 255) / 256, 256, 0, stream>>>(edge, cursor, sorted, E);
        edge_mlp_sorted<<<(E + BLK - 1) / BLK, BLK, 0, stream>>>(
            last_coors, last_features, current_coors, edge, sorted,
            W1, b1, W2, b2, agg, E);
        out_mlp_f32<<<(M + BLK - 1) / BLK, BLK, 0, stream>>>(agg, W3, b3, W4, b4, M);
    }
}